// Round 1
// baseline (46.000 us; speedup 1.0000x reference)
//
#include <hip/hip_runtime.h>

#define VOCAB 2048
#define D_MODEL 512
#define MAX_LEN 40000

// ---------------------------------------------------------------------------
// Kernel 1: init first_seen[v] = L, rank[v] = 0
// ---------------------------------------------------------------------------
__global__ void tpe_init_kernel(int* __restrict__ fs, int* __restrict__ rnk, int L) {
    int v = blockIdx.x * blockDim.x + threadIdx.x;
    if (v < VOCAB) {
        fs[v]  = L;
        rnk[v] = 0;
    }
}

// ---------------------------------------------------------------------------
// Kernel 2: first_seen[v] = min position where token v occurs
// ---------------------------------------------------------------------------
__global__ void tpe_firstseen_kernel(const int* __restrict__ tok, int* __restrict__ fs, int L) {
    int i = blockIdx.x * blockDim.x + threadIdx.x;
    if (i < L) {
        int t = tok[i];
        atomicMin(&fs[t], i);
    }
}

// ---------------------------------------------------------------------------
// Kernel 3: rank[v] = #{ u : first_seen[u] < first_seen[v] }
// (= first-seen-order index of type v; absent types get garbage ranks but are
//  never looked up). Work split: 64 blocks x 256 threads; block b handles
//  v in [(b>>3)*256, ...+256) against u-chunk (b&7)*256..+256, partial counts
//  accumulated with atomicAdd. fs[ubase+i] is wave-uniform -> scalar loads.
// ---------------------------------------------------------------------------
__global__ void tpe_rank_kernel(const int* __restrict__ fs, int* __restrict__ rnk) {
    int t     = threadIdx.x;
    int vbase = (blockIdx.x >> 3) * 256;
    int ubase = (blockIdx.x & 7) * 256;
    int v  = vbase + t;
    int my = fs[v];
    int c = 0;
#pragma unroll 16
    for (int i = 0; i < 256; ++i) {
        c += (fs[ubase + i] < my) ? 1 : 0;
    }
    atomicAdd(&rnk[v], c);
}

// ---------------------------------------------------------------------------
// Kernel 4: out[i, :] = x[i, :] + pe[min(rank[tok[i]], MAX_LEN-1), :]
// float4-vectorized: 128 float4 per row.
// ---------------------------------------------------------------------------
__global__ void tpe_add_kernel(const float4* __restrict__ x,
                               const float*  __restrict__ pe,
                               const int*    __restrict__ tok,
                               const int*    __restrict__ rnk,
                               float4*       __restrict__ out,
                               int n4) {
    int idx = blockIdx.x * blockDim.x + threadIdx.x;
    if (idx >= n4) return;
    int row = idx >> 7;          // D_MODEL/4 = 128 float4 per row
    int col = idx & 127;
    int p = rnk[tok[row]];
    p = (p < MAX_LEN - 1) ? p : (MAX_LEN - 1);
    const float4* per = reinterpret_cast<const float4*>(pe + (size_t)p * D_MODEL);
    float4 a = x[idx];
    float4 b = per[col];
    out[idx] = make_float4(a.x + b.x, a.y + b.y, a.z + b.z, a.w + b.w);
}

extern "C" void kernel_launch(void* const* d_in, const int* in_sizes, int n_in,
                              void* d_out, int out_size, void* d_ws, size_t ws_size,
                              hipStream_t stream) {
    const int*   tok = (const int*)d_in[0];    // (1, L) int
    const float* x   = (const float*)d_in[1];  // (1, L, 512) f32
    const float* pe  = (const float*)d_in[2];  // (1, 40000, 512) f32
    float* out = (float*)d_out;

    const int L = in_sizes[0];                 // 32768

    int* fs  = (int*)d_ws;                     // [VOCAB]
    int* rnk = fs + VOCAB;                     // [VOCAB]

    // 1. init
    tpe_init_kernel<<<(VOCAB + 255) / 256, 256, 0, stream>>>(fs, rnk, L);

    // 2. first-seen positions
    tpe_firstseen_kernel<<<(L + 255) / 256, 256, 0, stream>>>(tok, fs, L);

    // 3. ranks (first-seen order)
    tpe_rank_kernel<<<(VOCAB / 256) * 8, 256, 0, stream>>>(fs, rnk);

    // 4. gather + add
    int n4 = L * (D_MODEL / 4);
    tpe_add_kernel<<<(n4 + 255) / 256, 256, 0, stream>>>(
        (const float4*)x, pe, tok, rnk, (float4*)out, n4);
}

// Round 2
// 37.574 us; speedup vs baseline: 1.2242x; 1.2242x over previous
//
#include <hip/hip_runtime.h>

#define VOCAB 2048
#define D_MODEL 512
#define MAX_LEN 40000
#define MAX_L 32768          // max sequence length supported by bitmask (L in setup = 32768)

typedef float f32x4 __attribute__((ext_vector_type(4)));

// ---------------------------------------------------------------------------
// Kernel 1 (single workgroup, 1024 threads): full index prep.
//   fs[v]   = first position token v occurs (L if never)        [LDS atomicMin]
//   mask    = bit i set iff i is a first-occurrence position    [LDS atomicOr]
//   pref[w] = exclusive prefix popcount over mask words         [shfl scan]
//   rnk[v]  = min(#first-occurrences at positions < fs[v], MAX_LEN-1) -> global
// ---------------------------------------------------------------------------
__global__ __launch_bounds__(1024) void tpe_prep_kernel(const int* __restrict__ tok,
                                                        int* __restrict__ rnk,
                                                        int L) {
    __shared__ int      fs[VOCAB];            // 8 KB
    __shared__ unsigned bmask[MAX_L / 32];    // 4 KB
    __shared__ int      pref[MAX_L / 32];     // 4 KB
    __shared__ int      wtot[16];

    const int t    = threadIdx.x;
    const int lane = t & 63;
    const int wid  = t >> 6;

    // init
    fs[t]          = L;
    fs[t + 1024]   = L;
    bmask[t]       = 0u;
    __syncthreads();

    // first-seen: int4-vectorized token scan, atomicMin into LDS
    const int4* tok4 = reinterpret_cast<const int4*>(tok);
    const int n4 = L >> 2;
    for (int i = t; i < n4; i += 1024) {
        int4 v = tok4[i];
        int base = i << 2;
        atomicMin(&fs[v.x], base);
        atomicMin(&fs[v.y], base + 1);
        atomicMin(&fs[v.z], base + 2);
        atomicMin(&fs[v.w], base + 3);
    }
    __syncthreads();

    // mark first-occurrence positions
    {
        int p0 = fs[t];
        int p1 = fs[t + 1024];
        if (p0 < L) atomicOr(&bmask[p0 >> 5], 1u << (p0 & 31));
        if (p1 < L) atomicOr(&bmask[p1 >> 5], 1u << (p1 & 31));
    }
    __syncthreads();

    // exclusive prefix-sum of popcounts over 1024 words
    unsigned w = bmask[t];
    int c   = __popc(w);
    int inc = c;
    #pragma unroll
    for (int off = 1; off < 64; off <<= 1) {
        int n = __shfl_up(inc, off, 64);
        if (lane >= off) inc += n;
    }
    if (lane == 63) wtot[wid] = inc;
    __syncthreads();
    if (t < 16) {
        int s  = wtot[t];
        int is = s;
        #pragma unroll
        for (int off = 1; off < 16; off <<= 1) {
            int n = __shfl_up(is, off, 16);
            if (t >= off) is += n;
        }
        wtot[t] = is - s;   // exclusive wave offset
    }
    __syncthreads();
    pref[t] = wtot[wid] + inc - c;  // exclusive prefix of word t
    __syncthreads();

    // rank per vocab id -> global (clamped)
    #pragma unroll
    for (int k = 0; k < 2; ++k) {
        int v = t + k * 1024;
        int p = fs[v];
        int r = 0;
        if (p < L) {
            r = pref[p >> 5] + __popc(bmask[p >> 5] & ((1u << (p & 31)) - 1u));
        }
        rnk[v] = (r < MAX_LEN - 1) ? r : (MAX_LEN - 1);
    }
}

// ---------------------------------------------------------------------------
// Kernel 2: out[i, :] = x[i, :] + pe[rnk[tok[i]], :]
// float4-vectorized, non-temporal on the streaming x/out traffic so the
// gathered pe rows (<=4 MB) stay L2-resident.
// ---------------------------------------------------------------------------
__global__ __launch_bounds__(256) void tpe_add_kernel(const f32x4* __restrict__ x,
                                                      const f32x4* __restrict__ pe,
                                                      const int*   __restrict__ tok,
                                                      const int*   __restrict__ rnk,
                                                      f32x4*       __restrict__ out,
                                                      int n4) {
    int idx = blockIdx.x * blockDim.x + threadIdx.x;
    if (idx >= n4) return;
    int row = idx >> 7;          // D_MODEL/4 = 128 float4 per row
    int col = idx & 127;
    int p = rnk[tok[row]];       // wave-uniform -> broadcast loads
    f32x4 a = __builtin_nontemporal_load(&x[idx]);
    f32x4 b = pe[p * (D_MODEL / 4) + col];
    __builtin_nontemporal_store(a + b, &out[idx]);
}

extern "C" void kernel_launch(void* const* d_in, const int* in_sizes, int n_in,
                              void* d_out, int out_size, void* d_ws, size_t ws_size,
                              hipStream_t stream) {
    const int*   tok = (const int*)d_in[0];    // (1, L) int
    const float* x   = (const float*)d_in[1];  // (1, L, 512) f32
    const float* pe  = (const float*)d_in[2];  // (1, 40000, 512) f32
    float* out = (float*)d_out;

    const int L = in_sizes[0];                 // 32768

    int* rnk = (int*)d_ws;                     // [VOCAB]

    tpe_prep_kernel<<<1, 1024, 0, stream>>>(tok, rnk, L);

    int n4 = L * (D_MODEL / 4);
    tpe_add_kernel<<<(n4 + 255) / 256, 256, 0, stream>>>(
        (const f32x4*)x, (const f32x4*)pe, tok, rnk, (f32x4*)out, n4);
}